// Round 7
// baseline (262.918 us; speedup 1.0000x reference)
//
#include <hip/hip_runtime.h>

// Flash-attention fwd, causal GQA, paged KV. fp32 in/out, bf16 MFMA compute.
// Round 7: round-5 core (32x32 swapped MFMA, in-reg softmax, T12/T13, static
// balance 512 blocks x 2 items) but SINGLE-buffered LDS (32KB) with
// stage->barrier->compute->barrier per tile, __launch_bounds__(256,4)
// -> 4 blocks/CU (16 waves/CU) for cross-block phase-diverse overlap.
// (Round 6's read-hoist spilled to scratch at 128 VGPR: FETCH/WRITE tripled.)

#define SEQ   1024
#define NHQ   32
#define NHK   8
#define DH    128
#define BSZ   256
#define NBLK  16
#define QBLK  128
#define KVBLK 64
#define SCALE  0.0883883476483184f           // 1/sqrt(128)
#define SCLOG2 0.12752551286084812f          // SCALE * log2(e)

typedef __attribute__((ext_vector_type(8)))  short bf16x8;
typedef __attribute__((ext_vector_type(4)))  float f32x4;
typedef __attribute__((ext_vector_type(16))) float f32x16;
typedef __attribute__((ext_vector_type(2)))  unsigned int u32x2;
typedef unsigned short u16;
typedef unsigned int u32;
typedef unsigned long long u64;

static __device__ __forceinline__ u16 f2bf(float f) {
  union { float f; u32 u; } x; x.f = f;
  return (u16)((x.u + 0x7fffu + ((x.u >> 16) & 1u)) >> 16);  // RNE
}

static __device__ __forceinline__ u32 cvtpk(float a, float b) {
  u32 r;
  asm("v_cvt_pk_bf16_f32 %0, %1, %2" : "=v"(r) : "v"(a), "v"(b));
  return r;
}

static __device__ __forceinline__ void gload16(const u16* src, u16* dst_lds) {
  __builtin_amdgcn_global_load_lds(
      (const __attribute__((address_space(1))) u32*)src,
      (__attribute__((address_space(3))) u32*)dst_lds, 16, 0, 0);
}

// ---------------- preprocess: fp32 KV -> bf16 K[nb][hk][key][d], V^T[nb][hk][d][key] ----------------
__global__ void prep_kv(const float* __restrict__ kc, const float* __restrict__ vc,
                        u16* __restrict__ kb, u16* __restrict__ vbT) {
  const int idx = blockIdx.x * 256 + threadIdx.x;   // (nb, key, hk, d4), d4 fastest
  const int d4  = idx & 31;
  const int hk  = (idx >> 5) & 7;
  const int key = (idx >> 8) & 255;
  const int nb  = idx >> 16;
  f32x4 kx = *(const f32x4*)(kc + (size_t)idx * 4);
  f32x4 vx = *(const f32x4*)(vc + (size_t)idx * 4);
  u64 pk = (u64)f2bf(kx[0]) | ((u64)f2bf(kx[1]) << 16) |
           ((u64)f2bf(kx[2]) << 32) | ((u64)f2bf(kx[3]) << 48);
  *(u64*)(kb + (((size_t)(nb * NHK + hk) * BSZ + key) * DH + 4 * d4)) = pk;
#pragma unroll
  for (int j = 0; j < 4; ++j)
    vbT[((size_t)(nb * NHK + hk) * DH + 4 * d4 + j) * BSZ + key] = f2bf(vx[j]);
}

// ---------------- main attention: 4 warps x 32 q-rows, 2 balanced items/block ----------------
__global__ __launch_bounds__(256, 4)
void attn_fwd_pre(const float* __restrict__ qg,
                  const u16* __restrict__ kbg,
                  const u16* __restrict__ vbT,
                  const int* __restrict__ btab,
                  float* __restrict__ outg)
{
  __shared__ u16 lk[KVBLK * DH];   // 16 KB, K [key][d], content slot-swizzled (&15)
  __shared__ u16 lv[DH * KVBLK];   // 16 KB, V^T [d][key], slot-swizzled (&7)

  const int tid  = threadIdx.x;
  const int lane = tid & 63;
  const int w    = tid >> 6;     // 0..3
  const int ln   = lane & 31;
  const int hi   = lane >> 5;
  const int bid  = blockIdx.x;   // 0..511

  for (int item = 0; item < 2; ++item) {
    // items sorted by qc descending: it -> qc = 7-(it>>7); pair (bid, 1023-bid)
    const int it = item == 0 ? bid : 1023 - bid;
    const int qc = 7 - (it >> 7);
    const int rr = it & 127;
    const int hq = rr >> 2;
    const int b  = rr & 3;
    const int hk = hq >> 2;

    const int rg = qc * QBLK + w * 32 + ln;      // this lane's q-row (absolute)

    // ---- Q fragments (B-operand): qf[dc][j] = Q[rg][dc*16 + hi*8 + j] * SCLOG2 ----
    bf16x8 qf[8];
    {
      const float* qp = qg + ((size_t)(b * SEQ + rg) * NHQ + hq) * DH;
#pragma unroll
      for (int dc = 0; dc < 8; ++dc) {
        const int d0 = dc * 16 + hi * 8;
        f32x4 x0 = *(const f32x4*)(qp + d0);
        f32x4 x1 = *(const f32x4*)(qp + d0 + 4);
        bf16x8 f;
#pragma unroll
        for (int j = 0; j < 4; ++j) {
          f[j]     = (short)f2bf(x0[j] * SCLOG2);
          f[j + 4] = (short)f2bf(x1[j] * SCLOG2);
        }
        qf[dc] = f;
      }
    }

    f32x16 o[4];
#pragma unroll
    for (int db = 0; db < 4; ++db)
#pragma unroll
      for (int i = 0; i < 16; ++i) o[db][i] = 0.f;
    float m = -1e30f, l = 0.f;

    const u16* kbh = kbg + (size_t)hk * BSZ * DH;
    const u16* vbh = vbT + (size_t)hk * DH * BSZ;

    // stage tile t: 8 global_load_lds per warp, pre-swizzled source.
    auto stage = [&](int t) {
      const int nb   = btab[b * (SEQ / BSZ) + (t >> 2)];
      const int off0 = (t & 3) * KVBLK;
      const u16* ksrc = kbh + (size_t)nb * (NHK * BSZ * DH) + (size_t)off0 * DH;
      const u16* vsrc = vbh + (size_t)nb * (NHK * DH * BSZ) + off0;
      // K: warp w stages keys w*16 .. w*16+15 (4 instrs x 1KB), 16-granule swizzle.
#pragma unroll
      for (int i = 0; i < 4; ++i) {
        const int kbs = w * 16 + i * 4;
        const int key = kbs + (lane >> 4);
        const u16* src = ksrc + key * DH + 8 * ((lane & 15) ^ (key & 15));
        gload16(src, &lk[kbs * DH]);
      }
      // V^T: warp w stages d-rows w*32 .. w*32+31 (4 instrs x 1KB), 8-granule swizzle.
#pragma unroll
      for (int i = 0; i < 4; ++i) {
        const int dbs = w * 32 + i * 8;
        const int d   = dbs + (lane >> 3);
        const u16* src = vsrc + d * BSZ + 8 * ((lane & 7) ^ (d & 7));
        gload16(src, &lv[dbs * KVBLK]);
      }
    };

    const int ntile = 2 * qc + 2;
    const int tmaxw = 2 * qc + (w >> 1);   // last tile this warp computes

    for (int t = 0; t < ntile; ++t) {
      stage(t);
      __syncthreads();      // vmcnt drained; tile resident

      if (t <= tmaxw) {
        // ---- S^T = K·Q (swapped): lane holds S[rg][key] for 32 keys per kb ----
        f32x16 sa[2];
        __builtin_amdgcn_s_setprio(1);
#pragma unroll
        for (int kb = 0; kb < 2; ++kb) {
          f32x16 acc;
#pragma unroll
          for (int i = 0; i < 16; ++i) acc[i] = 0.f;
          const int key  = kb * 32 + ln;
          const int srow = key * DH;
          const int sw   = (key & 15) * 8;
#pragma unroll
          for (int dc = 0; dc < 8; ++dc) {
            const int d0 = dc * 16 + hi * 8;
            bf16x8 kf = *(const bf16x8*)&lk[srow + (d0 ^ sw)];
            acc = __builtin_amdgcn_mfma_f32_32x32x16_bf16(kf, qf[dc], acc, 0, 0, 0);
          }
          sa[kb] = acc;
        }
        __builtin_amdgcn_s_setprio(0);

        // ---- causal mask (diagonal tile only) ----
        if (t == tmaxw) {
          const int kt = t * KVBLK;
#pragma unroll
          for (int kb = 0; kb < 2; ++kb)
#pragma unroll
            for (int r = 0; r < 16; ++r) {
              const int kglob = kt + kb * 32 + (r & 3) + 8 * (r >> 2) + 4 * hi;
              if (kglob > rg) sa[kb][r] = -1e30f;
            }
        }

        // ---- row max: max3-friendly tree + one partner swap ----
        float mx[8];
#pragma unroll
        for (int i = 0; i < 8; ++i)
          mx[i] = fmaxf(fmaxf(sa[0][i], sa[0][i + 8]), fmaxf(sa[1][i], sa[1][i + 8]));
        float m0 = fmaxf(fmaxf(mx[0], mx[1]), fmaxf(mx[2], mx[3]));
        float m1 = fmaxf(fmaxf(mx[4], mx[5]), fmaxf(mx[6], mx[7]));
        m0 = fmaxf(m0, m1);
        u32x2 xr = __builtin_amdgcn_permlane32_swap(
            __float_as_uint(m0), __float_as_uint(m0), false, false);
        const float tmax = fmaxf(__uint_as_float(xr[0]), __uint_as_float(xr[1]));

        // ---- deferred rescale (T13; log2 domain, THR=11 bits ~ e^7.6) ----
        if (tmax > m + 11.0f) {
          const float corr = exp2f(m - tmax);
          m = tmax;
          l *= corr;
#pragma unroll
          for (int db = 0; db < 4; ++db)
#pragma unroll
            for (int i = 0; i < 16; ++i) o[db][i] *= corr;
        }

        // ---- P = 2^(s - m); row sum (in-lane tree + partner swap) ----
        float sm[16];
#pragma unroll
        for (int i = 0; i < 16; ++i) {
          sa[0][i] = exp2f(sa[0][i] - m);
          sa[1][i] = exp2f(sa[1][i] - m);
          sm[i] = sa[0][i] + sa[1][i];
        }
#pragma unroll
        for (int st = 8; st >= 1; st >>= 1)
#pragma unroll
          for (int i = 0; i < st; ++i) sm[i] += sm[i + st];
        u32x2 sr = __builtin_amdgcn_permlane32_swap(
            __float_as_uint(sm[0]), __float_as_uint(sm[0]), false, false);
        l += __uint_as_float(sr[0]) + __uint_as_float(sr[1]);

        // ---- PV: O^T += V^T · P^T ; P->B-frag via cvt_pk + permlane32_swap (T12) ----
#pragma unroll
        for (int kc = 0; kc < 4; ++kc) {
          const int kb = kc >> 1, cc = kc & 1;
          const u32 x0 = cvtpk(sa[kb][8 * cc + 0], sa[kb][8 * cc + 1]);
          const u32 y0 = cvtpk(sa[kb][8 * cc + 4], sa[kb][8 * cc + 5]);
          const u32 x1 = cvtpk(sa[kb][8 * cc + 2], sa[kb][8 * cc + 3]);
          const u32 y1 = cvtpk(sa[kb][8 * cc + 6], sa[kb][8 * cc + 7]);
          u32x2 r0 = __builtin_amdgcn_permlane32_swap(x0, y0, false, false);
          u32x2 r1 = __builtin_amdgcn_permlane32_swap(x1, y1, false, false);
          union { bf16x8 v; u32 u[4]; } pb;
          pb.u[0] = r0[0]; pb.u[1] = r1[0]; pb.u[2] = r0[1]; pb.u[3] = r1[1];
          const int k0 = kc * 16 + hi * 8;
          __builtin_amdgcn_s_setprio(1);
#pragma unroll
          for (int db = 0; db < 4; ++db) {
            const int d = db * 32 + ln;
            bf16x8 vf = *(const bf16x8*)&lv[d * KVBLK + (k0 ^ ((d & 7) * 8))];
            o[db] = __builtin_amdgcn_mfma_f32_32x32x16_bf16(vf, pb.v, o[db], 0, 0, 0);
          }
          __builtin_amdgcn_s_setprio(0);
        }
      }

      __syncthreads();      // LDS reads done before next tile's stage overwrites
    }

    // ---- epilogue: O[rg][d] / l ; d = db*32 + (reg&3) + 8*(reg>>2) + 4*hi ----
    const float inv = 1.0f / l;
    float* op = outg + ((size_t)(b * SEQ + rg) * NHQ + hq) * DH;
#pragma unroll
    for (int db = 0; db < 4; ++db)
#pragma unroll
      for (int q4 = 0; q4 < 4; ++q4) {
        f32x4 val;
#pragma unroll
        for (int r2 = 0; r2 < 4; ++r2) val[r2] = o[db][q4 * 4 + r2] * inv;
        *(f32x4*)(op + db * 32 + q4 * 8 + hi * 4) = val;
      }
  }
}

// ---------------- fallback (fp32 caches, no ws), round-1 structure ----------------
__global__ __launch_bounds__(256, 2)
void attn_fwd_fb(const float* __restrict__ qg,
                 const float* __restrict__ kcache,
                 const float* __restrict__ vcache,
                 const int*   __restrict__ btab,
                 float* __restrict__ outg)
{
  __shared__ u16 lk[KVBLK * DH];
  __shared__ u16 lv[DH * KVBLK];
  __shared__ u16 lp[4][16 * KVBLK];

  const int tid  = threadIdx.x;
  const int lane = tid & 63;
  const int w    = tid >> 6;
  const int qt   = blockIdx.x;
  const int hq   = blockIdx.y;
  const int b    = blockIdx.z;
  const int hk   = hq >> 2;
  const int qbase = qt * 64;
  const int cl = lane & 15;
  const int kg = lane >> 4;

  bf16x8 qf[4];
  {
    const int tq = qbase + w * 16 + cl;
    const float* qp = qg + ((size_t)(b * SEQ + tq) * NHQ + hq) * DH;
#pragma unroll
    for (int dc = 0; dc < 4; ++dc) {
      const int d0 = dc * 32 + kg * 8;
      f32x4 x0 = *(const f32x4*)(qp + d0);
      f32x4 x1 = *(const f32x4*)(qp + d0 + 4);
      bf16x8 f;
#pragma unroll
      for (int j = 0; j < 4; ++j) { f[j] = (short)f2bf(x0[j] * SCALE); f[j + 4] = (short)f2bf(x1[j] * SCALE); }
      qf[dc] = f;
    }
  }

  f32x4 o[8];
#pragma unroll
  for (int i = 0; i < 8; ++i) o[i] = (f32x4){0.f, 0.f, 0.f, 0.f};
  float mrow[4] = {-1e30f, -1e30f, -1e30f, -1e30f};
  float lrow[4] = {0.f, 0.f, 0.f, 0.f};

  const int ntile = qt + 1;
  for (int t = 0; t < ntile; ++t) {
    __syncthreads();
    {
      const int nb   = btab[b * (SEQ / BSZ) + ((t * KVBLK) / BSZ)];
      const int off0 = (t * KVBLK) % BSZ;
      const int d4 = tid & 31;
      const int kl = tid >> 5;
      const float* kbp = kcache + (((size_t)nb * BSZ + off0) * NHK + hk) * DH + d4 * 4;
      const float* vbp = vcache + (((size_t)nb * BSZ + off0) * NHK + hk) * DH + d4 * 4;
#pragma unroll
      for (int p = 0; p < 8; ++p) {
        const int key = p * 8 + kl;
        const size_t go = (size_t)key * (NHK * DH);
        f32x4 kx = *(const f32x4*)(kbp + go);
        f32x4 vx = *(const f32x4*)(vbp + go);
        u32 w0 = (u32)f2bf(kx[0]) | ((u32)f2bf(kx[1]) << 16);
        u32 w1 = (u32)f2bf(kx[2]) | ((u32)f2bf(kx[3]) << 16);
        const int doff = (4 * d4) ^ ((key & 7) * 8);
        u64 pk = (u64)w0 | ((u64)w1 << 32);
        *(u64*)&lk[key * DH + doff] = pk;
#pragma unroll
        for (int j = 0; j < 4; ++j) {
          const int d = 4 * d4 + j;
          lv[d * KVBLK + (key ^ ((d & 7) * 8))] = f2bf(vx[j]);
        }
      }
    }
    __syncthreads();

    float s[4][4];
#pragma unroll
    for (int ct = 0; ct < 4; ++ct) {
      f32x4 acc = (f32x4){0.f, 0.f, 0.f, 0.f};
      const int key = ct * 16 + cl;
#pragma unroll
      for (int dc = 0; dc < 4; ++dc) {
        const int d0 = (dc * 32 + kg * 8) ^ ((key & 7) * 8);
        bf16x8 kf = *(const bf16x8*)&lk[key * DH + d0];
        acc = __builtin_amdgcn_mfma_f32_16x16x32_bf16(qf[dc], kf, acc, 0, 0, 0);
      }
#pragma unroll
      for (int v = 0; v < 4; ++v) s[ct][v] = acc[v];
    }
    if (t == qt) {
      const int rbase = w * 16 + kg * 4;
#pragma unroll
      for (int ct = 0; ct < 4; ++ct) {
        const int key = ct * 16 + cl;
#pragma unroll
        for (int v = 0; v < 4; ++v)
          if (key > rbase + v) s[ct][v] = -1e30f;
      }
    }
    float corr[4];
#pragma unroll
    for (int v = 0; v < 4; ++v) {
      float x = fmaxf(fmaxf(s[0][v], s[1][v]), fmaxf(s[2][v], s[3][v]));
#pragma unroll
      for (int off = 1; off < 16; off <<= 1) x = fmaxf(x, __shfl_xor(x, off));
      const float mn = fmaxf(mrow[v], x);
      corr[v] = __expf(mrow[v] - mn);
      mrow[v] = mn;
    }
    float rs[4] = {0.f, 0.f, 0.f, 0.f};
    u16 pb[4][4];
#pragma unroll
    for (int ct = 0; ct < 4; ++ct)
#pragma unroll
      for (int v = 0; v < 4; ++v) {
        const float p = __expf(s[ct][v] - mrow[v]);
        rs[v] += p;
        pb[ct][v] = f2bf(p);
      }
#pragma unroll
    for (int v = 0; v < 4; ++v) {
      float x = rs[v];
#pragma unroll
      for (int off = 1; off < 16; off <<= 1) x += __shfl_xor(x, off);
      lrow[v] = lrow[v] * corr[v] + x;
    }
#pragma unroll
    for (int dt = 0; dt < 8; ++dt)
#pragma unroll
      for (int v = 0; v < 4; ++v) o[dt][v] *= corr[v];

    u16* pw = &lp[w][0];
#pragma unroll
    for (int ct = 0; ct < 4; ++ct)
#pragma unroll
      for (int v = 0; v < 4; ++v) {
        const int r = kg * 4 + v;
        const int cc = ct * 16 + cl;
        pw[r * KVBLK + (cc ^ ((r & 7) * 8))] = pb[ct][v];
      }
    bf16x8 pa[2];
#pragma unroll
    for (int kc2 = 0; kc2 < 2; ++kc2) {
      const int c0 = (kc2 * 32 + kg * 8) ^ ((cl & 7) * 8);
      pa[kc2] = *(const bf16x8*)&pw[cl * KVBLK + c0];
    }
#pragma unroll
    for (int dt = 0; dt < 8; ++dt) {
      const int d = dt * 16 + cl;
#pragma unroll
      for (int kc2 = 0; kc2 < 2; ++kc2) {
        const int c0 = (kc2 * 32 + kg * 8) ^ ((d & 7) * 8);
        bf16x8 vf = *(const bf16x8*)&lv[d * KVBLK + c0];
        o[dt] = __builtin_amdgcn_mfma_f32_16x16x32_bf16(pa[kc2], vf, o[dt], 0, 0, 0);
      }
    }
  }

#pragma unroll
  for (int v = 0; v < 4; ++v) {
    const float inv = 1.0f / lrow[v];
    const int tq = qbase + w * 16 + kg * 4 + v;
    float* op = outg + ((size_t)(b * SEQ + tq) * NHQ + hq) * DH;
#pragma unroll
    for (int dt = 0; dt < 8; ++dt) op[dt * 16 + cl] = o[dt][v] * inv;
  }
}

extern "C" void kernel_launch(void* const* d_in, const int* in_sizes, int n_in,
                              void* d_out, int out_size, void* d_ws, size_t ws_size,
                              hipStream_t stream) {
  const float* q  = (const float*)d_in[0];
  const float* kc = (const float*)d_in[1];
  const float* vc = (const float*)d_in[2];
  const int*   bt = (const int*)d_in[3];
  float* out = (float*)d_out;
  const size_t kv_elems = (size_t)NBLK * NHK * BSZ * DH;
  const size_t need = 2 * kv_elems * sizeof(u16);   // 16.8 MB
  if (ws_size >= need) {
    u16* kb  = (u16*)d_ws;
    u16* vbT = kb + kv_elems;
    const int total_quads = NBLK * BSZ * NHK * (DH / 4);
    prep_kv<<<total_quads / 256, 256, 0, stream>>>(kc, vc, kb, vbT);
    attn_fwd_pre<<<dim3(512), 256, 0, stream>>>(q, kb, vbT, bt, out);
  } else {
    dim3 grid_fb(SEQ / 64, NHQ, 4 /*B*/);
    attn_fwd_fb<<<grid_fb, 256, 0, stream>>>(q, kc, vc, bt, out);
  }
}

// Round 8
// 182.048 us; speedup vs baseline: 1.4442x; 1.4442x over previous
//
#include <hip/hip_runtime.h>

// Flash-attention fwd, causal GQA, paged KV. fp32 in/out, bf16 MFMA compute.
// Round 8: round-5 body, occupancy move done right:
//  - LDS 48KB: K double-buffered (2x16KB, prefetch kept), V single-buffered
//    (16KB) with stage->[QKT+softmax]->barrierA->PV->barrierB. 3 blocks/CU.
//  - Register budget via amdgpu_waves_per_eu(3) (512/3~170 total regs), NOT
//    launch_bounds' 2nd arg (r7 showed that forces 256/arg and spills).
// Core: 32x32 swapped MFMA, in-reg softmax (permlane32_swap), T12 cvt_pk,
// T13 defer-max, static balance (512 blocks x 2 items, 18 units each),
// K swizzle &15 / V swizzle &7, bf16 KV preprocessed into d_ws.

#define SEQ   1024
#define NHQ   32
#define NHK   8
#define DH    128
#define BSZ   256
#define NBLK  16
#define QBLK  128
#define KVBLK 64
#define SCALE  0.0883883476483184f           // 1/sqrt(128)
#define SCLOG2 0.12752551286084812f          // SCALE * log2(e)

typedef __attribute__((ext_vector_type(8)))  short bf16x8;
typedef __attribute__((ext_vector_type(4)))  float f32x4;
typedef __attribute__((ext_vector_type(16))) float f32x16;
typedef __attribute__((ext_vector_type(2)))  unsigned int u32x2;
typedef unsigned short u16;
typedef unsigned int u32;
typedef unsigned long long u64;

static __device__ __forceinline__ u16 f2bf(float f) {
  union { float f; u32 u; } x; x.f = f;
  return (u16)((x.u + 0x7fffu + ((x.u >> 16) & 1u)) >> 16);  // RNE
}

static __device__ __forceinline__ u32 cvtpk(float a, float b) {
  u32 r;
  asm("v_cvt_pk_bf16_f32 %0, %1, %2" : "=v"(r) : "v"(a), "v"(b));
  return r;
}

static __device__ __forceinline__ void gload16(const u16* src, u16* dst_lds) {
  __builtin_amdgcn_global_load_lds(
      (const __attribute__((address_space(1))) u32*)src,
      (__attribute__((address_space(3))) u32*)dst_lds, 16, 0, 0);
}

// ---------------- preprocess: fp32 KV -> bf16 K[nb][hk][key][d], V^T[nb][hk][d][key] ----------------
__global__ void prep_kv(const float* __restrict__ kc, const float* __restrict__ vc,
                        u16* __restrict__ kb, u16* __restrict__ vbT) {
  const int idx = blockIdx.x * 256 + threadIdx.x;   // (nb, key, hk, d4), d4 fastest
  const int d4  = idx & 31;
  const int hk  = (idx >> 5) & 7;
  const int key = (idx >> 8) & 255;
  const int nb  = idx >> 16;
  f32x4 kx = *(const f32x4*)(kc + (size_t)idx * 4);
  f32x4 vx = *(const f32x4*)(vc + (size_t)idx * 4);
  u64 pk = (u64)f2bf(kx[0]) | ((u64)f2bf(kx[1]) << 16) |
           ((u64)f2bf(kx[2]) << 32) | ((u64)f2bf(kx[3]) << 48);
  *(u64*)(kb + (((size_t)(nb * NHK + hk) * BSZ + key) * DH + 4 * d4)) = pk;
#pragma unroll
  for (int j = 0; j < 4; ++j)
    vbT[((size_t)(nb * NHK + hk) * DH + 4 * d4 + j) * BSZ + key] = f2bf(vx[j]);
}

// ---------------- main attention: 4 warps x 32 q-rows, 2 balanced items/block ----------------
__global__ __launch_bounds__(256) __attribute__((amdgpu_waves_per_eu(3)))
void attn_fwd_pre(const float* __restrict__ qg,
                  const u16* __restrict__ kbg,
                  const u16* __restrict__ vbT,
                  const int* __restrict__ btab,
                  float* __restrict__ outg)
{
  __shared__ u16 lk[2][KVBLK * DH];   // 2 x 16 KB, K [key][d], slot-swizzled (&15)
  __shared__ u16 lv[DH * KVBLK];      // 16 KB, V^T [d][key], slot-swizzled (&7)

  const int tid  = threadIdx.x;
  const int lane = tid & 63;
  const int w    = tid >> 6;     // 0..3
  const int ln   = lane & 31;
  const int hi   = lane >> 5;
  const int bid  = blockIdx.x;   // 0..511

  for (int item = 0; item < 2; ++item) {
    // items sorted by qc descending: it -> qc = 7-(it>>7); pair (bid, 1023-bid)
    const int it = item == 0 ? bid : 1023 - bid;
    const int qc = 7 - (it >> 7);
    const int rr = it & 127;
    const int hq = rr >> 2;
    const int b  = rr & 3;
    const int hk = hq >> 2;

    const int rg = qc * QBLK + w * 32 + ln;      // this lane's q-row (absolute)

    // ---- Q fragments (B-operand): qf[dc][j] = Q[rg][dc*16 + hi*8 + j] * SCLOG2 ----
    bf16x8 qf[8];
    {
      const float* qp = qg + ((size_t)(b * SEQ + rg) * NHQ + hq) * DH;
#pragma unroll
      for (int dc = 0; dc < 8; ++dc) {
        const int d0 = dc * 16 + hi * 8;
        f32x4 x0 = *(const f32x4*)(qp + d0);
        f32x4 x1 = *(const f32x4*)(qp + d0 + 4);
        bf16x8 f;
#pragma unroll
        for (int j = 0; j < 4; ++j) {
          f[j]     = (short)f2bf(x0[j] * SCLOG2);
          f[j + 4] = (short)f2bf(x1[j] * SCLOG2);
        }
        qf[dc] = f;
      }
    }

    f32x16 o[4];
#pragma unroll
    for (int db = 0; db < 4; ++db)
#pragma unroll
      for (int i = 0; i < 16; ++i) o[db][i] = 0.f;
    float m = -1e30f, l = 0.f;

    const u16* kbh = kbg + (size_t)hk * BSZ * DH;
    const u16* vbh = vbT + (size_t)hk * DH * BSZ;

    // K stage (tile t -> buffer c): 4 gload_lds per warp, pre-swizzled source.
    auto stage_k = [&](int t, int c) {
      const int nb   = btab[b * (SEQ / BSZ) + (t >> 2)];
      const int off0 = (t & 3) * KVBLK;
      const u16* ksrc = kbh + (size_t)nb * (NHK * BSZ * DH) + (size_t)off0 * DH;
#pragma unroll
      for (int i = 0; i < 4; ++i) {
        const int kbs = w * 16 + i * 4;
        const int key = kbs + (lane >> 4);
        const u16* src = ksrc + key * DH + 8 * ((lane & 15) ^ (key & 15));
        gload16(src, &lk[c][kbs * DH]);
      }
    };
    // V stage (tile t, single buffer): 4 gload_lds per warp.
    auto stage_v = [&](int t) {
      const int nb   = btab[b * (SEQ / BSZ) + (t >> 2)];
      const int off0 = (t & 3) * KVBLK;
      const u16* vsrc = vbh + (size_t)nb * (NHK * DH * BSZ) + off0;
#pragma unroll
      for (int i = 0; i < 4; ++i) {
        const int dbs = w * 32 + i * 8;
        const int d   = dbs + (lane >> 3);
        const u16* src = vsrc + d * BSZ + 8 * ((lane & 7) ^ (d & 7));
        gload16(src, &lv[dbs * KVBLK]);
      }
    };

    const int ntile = 2 * qc + 2;
    const int tmaxw = 2 * qc + (w >> 1);   // last tile this warp computes

    stage_k(0, 0);
    __syncthreads();                       // K(0) resident

    for (int t = 0; t < ntile; ++t) {
      const int c = t & 1;
      const bool live = (t <= tmaxw);

      stage_v(t);                          // V(t) -> lv (latency hides under QKT)
      if (t + 1 < ntile) stage_k(t + 1, c ^ 1);

      f32x16 sa[2];
      if (live) {
        // ---- S^T = K·Q (swapped): lane holds S[rg][key] for 32 keys per kb ----
        __builtin_amdgcn_s_setprio(1);
#pragma unroll
        for (int kb = 0; kb < 2; ++kb) {
          f32x16 acc;
#pragma unroll
          for (int i = 0; i < 16; ++i) acc[i] = 0.f;
          const int key  = kb * 32 + ln;
          const int srow = key * DH;
          const int sw   = (key & 15) * 8;
#pragma unroll
          for (int dc = 0; dc < 8; ++dc) {
            const int d0 = dc * 16 + hi * 8;
            bf16x8 kf = *(const bf16x8*)&lk[c][srow + (d0 ^ sw)];
            acc = __builtin_amdgcn_mfma_f32_32x32x16_bf16(kf, qf[dc], acc, 0, 0, 0);
          }
          sa[kb] = acc;
        }
        __builtin_amdgcn_s_setprio(0);

        // ---- causal mask (diagonal tile only) ----
        if (t == tmaxw) {
          const int kt = t * KVBLK;
#pragma unroll
          for (int kb = 0; kb < 2; ++kb)
#pragma unroll
            for (int r = 0; r < 16; ++r) {
              const int kglob = kt + kb * 32 + (r & 3) + 8 * (r >> 2) + 4 * hi;
              if (kglob > rg) sa[kb][r] = -1e30f;
            }
        }

        // ---- row max: max3-friendly tree + one partner swap ----
        float mx[8];
#pragma unroll
        for (int i = 0; i < 8; ++i)
          mx[i] = fmaxf(fmaxf(sa[0][i], sa[0][i + 8]), fmaxf(sa[1][i], sa[1][i + 8]));
        float m0 = fmaxf(fmaxf(mx[0], mx[1]), fmaxf(mx[2], mx[3]));
        float m1 = fmaxf(fmaxf(mx[4], mx[5]), fmaxf(mx[6], mx[7]));
        m0 = fmaxf(m0, m1);
        u32x2 xr = __builtin_amdgcn_permlane32_swap(
            __float_as_uint(m0), __float_as_uint(m0), false, false);
        const float tmax = fmaxf(__uint_as_float(xr[0]), __uint_as_float(xr[1]));

        // ---- deferred rescale (T13; log2 domain, THR=11 bits ~ e^7.6) ----
        if (tmax > m + 11.0f) {
          const float corr = exp2f(m - tmax);
          m = tmax;
          l *= corr;
#pragma unroll
          for (int db = 0; db < 4; ++db)
#pragma unroll
            for (int i = 0; i < 16; ++i) o[db][i] *= corr;
        }

        // ---- P = 2^(s - m); row sum (in-lane tree + partner swap) ----
        float sm[16];
#pragma unroll
        for (int i = 0; i < 16; ++i) {
          sa[0][i] = exp2f(sa[0][i] - m);
          sa[1][i] = exp2f(sa[1][i] - m);
          sm[i] = sa[0][i] + sa[1][i];
        }
#pragma unroll
        for (int st = 8; st >= 1; st >>= 1)
#pragma unroll
          for (int i = 0; i < st; ++i) sm[i] += sm[i + st];
        u32x2 sr = __builtin_amdgcn_permlane32_swap(
            __float_as_uint(sm[0]), __float_as_uint(sm[0]), false, false);
        l += __uint_as_float(sr[0]) + __uint_as_float(sr[1]);
      }

      __syncthreads();   // barrier A: V(t) (and K(t+1)) drained; lv readable

      if (live) {
        // ---- PV: O^T += V^T · P^T ; P->B-frag via cvt_pk + permlane32_swap (T12) ----
#pragma unroll
        for (int kc = 0; kc < 4; ++kc) {
          const int kb = kc >> 1, cc = kc & 1;
          const u32 x0 = cvtpk(sa[kb][8 * cc + 0], sa[kb][8 * cc + 1]);
          const u32 y0 = cvtpk(sa[kb][8 * cc + 4], sa[kb][8 * cc + 5]);
          const u32 x1 = cvtpk(sa[kb][8 * cc + 2], sa[kb][8 * cc + 3]);
          const u32 y1 = cvtpk(sa[kb][8 * cc + 6], sa[kb][8 * cc + 7]);
          u32x2 r0 = __builtin_amdgcn_permlane32_swap(x0, y0, false, false);
          u32x2 r1 = __builtin_amdgcn_permlane32_swap(x1, y1, false, false);
          union { bf16x8 v; u32 u[4]; } pb;
          pb.u[0] = r0[0]; pb.u[1] = r1[0]; pb.u[2] = r0[1]; pb.u[3] = r1[1];
          const int k0 = kc * 16 + hi * 8;
          __builtin_amdgcn_s_setprio(1);
#pragma unroll
          for (int db = 0; db < 4; ++db) {
            const int d = db * 32 + ln;
            bf16x8 vf = *(const bf16x8*)&lv[d * KVBLK + (k0 ^ ((d & 7) * 8))];
            o[db] = __builtin_amdgcn_mfma_f32_32x32x16_bf16(vf, pb.v, o[db], 0, 0, 0);
          }
          __builtin_amdgcn_s_setprio(0);
        }
      }

      __syncthreads();   // barrier B: lv reads done before next stage_v overwrite
    }

    // ---- epilogue: O[rg][d] / l ; d = db*32 + (reg&3) + 8*(reg>>2) + 4*hi ----
    const float inv = 1.0f / l;
    float* op = outg + ((size_t)(b * SEQ + rg) * NHQ + hq) * DH;
#pragma unroll
    for (int db = 0; db < 4; ++db)
#pragma unroll
      for (int q4 = 0; q4 < 4; ++q4) {
        f32x4 val;
#pragma unroll
        for (int r2 = 0; r2 < 4; ++r2) val[r2] = o[db][q4 * 4 + r2] * inv;
        *(f32x4*)(op + db * 32 + q4 * 8 + hi * 4) = val;
      }
  }
}

// ---------------- fallback (fp32 caches, no ws), round-1 structure ----------------
__global__ __launch_bounds__(256, 2)
void attn_fwd_fb(const float* __restrict__ qg,
                 const float* __restrict__ kcache,
                 const float* __restrict__ vcache,
                 const int*   __restrict__ btab,
                 float* __restrict__ outg)
{
  __shared__ u16 lk[KVBLK * DH];
  __shared__ u16 lv[DH * KVBLK];
  __shared__ u16 lp[4][16 * KVBLK];

  const int tid  = threadIdx.x;
  const int lane = tid & 63;
  const int w    = tid >> 6;
  const int qt   = blockIdx.x;
  const int hq   = blockIdx.y;
  const int b    = blockIdx.z;
  const int hk   = hq >> 2;
  const int qbase = qt * 64;
  const int cl = lane & 15;
  const int kg = lane >> 4;

  bf16x8 qf[4];
  {
    const int tq = qbase + w * 16 + cl;
    const float* qp = qg + ((size_t)(b * SEQ + tq) * NHQ + hq) * DH;
#pragma unroll
    for (int dc = 0; dc < 4; ++dc) {
      const int d0 = dc * 32 + kg * 8;
      f32x4 x0 = *(const f32x4*)(qp + d0);
      f32x4 x1 = *(const f32x4*)(qp + d0 + 4);
      bf16x8 f;
#pragma unroll
      for (int j = 0; j < 4; ++j) { f[j] = (short)f2bf(x0[j] * SCALE); f[j + 4] = (short)f2bf(x1[j] * SCALE); }
      qf[dc] = f;
    }
  }

  f32x4 o[8];
#pragma unroll
  for (int i = 0; i < 8; ++i) o[i] = (f32x4){0.f, 0.f, 0.f, 0.f};
  float mrow[4] = {-1e30f, -1e30f, -1e30f, -1e30f};
  float lrow[4] = {0.f, 0.f, 0.f, 0.f};

  const int ntile = qt + 1;
  for (int t = 0; t < ntile; ++t) {
    __syncthreads();
    {
      const int nb   = btab[b * (SEQ / BSZ) + ((t * KVBLK) / BSZ)];
      const int off0 = (t * KVBLK) % BSZ;
      const int d4 = tid & 31;
      const int kl = tid >> 5;
      const float* kbp = kcache + (((size_t)nb * BSZ + off0) * NHK + hk) * DH + d4 * 4;
      const float* vbp = vcache + (((size_t)nb * BSZ + off0) * NHK + hk) * DH + d4 * 4;
#pragma unroll
      for (int p = 0; p < 8; ++p) {
        const int key = p * 8 + kl;
        const size_t go = (size_t)key * (NHK * DH);
        f32x4 kx = *(const f32x4*)(kbp + go);
        f32x4 vx = *(const f32x4*)(vbp + go);
        u32 w0 = (u32)f2bf(kx[0]) | ((u32)f2bf(kx[1]) << 16);
        u32 w1 = (u32)f2bf(kx[2]) | ((u32)f2bf(kx[3]) << 16);
        const int doff = (4 * d4) ^ ((key & 7) * 8);
        u64 pk = (u64)w0 | ((u64)w1 << 32);
        *(u64*)&lk[key * DH + doff] = pk;
#pragma unroll
        for (int j = 0; j < 4; ++j) {
          const int d = 4 * d4 + j;
          lv[d * KVBLK + (key ^ ((d & 7) * 8))] = f2bf(vx[j]);
        }
      }
    }
    __syncthreads();

    float s[4][4];
#pragma unroll
    for (int ct = 0; ct < 4; ++ct) {
      f32x4 acc = (f32x4){0.f, 0.f, 0.f, 0.f};
      const int key = ct * 16 + cl;
#pragma unroll
      for (int dc = 0; dc < 4; ++dc) {
        const int d0 = (dc * 32 + kg * 8) ^ ((key & 7) * 8);
        bf16x8 kf = *(const bf16x8*)&lk[key * DH + d0];
        acc = __builtin_amdgcn_mfma_f32_16x16x32_bf16(qf[dc], kf, acc, 0, 0, 0);
      }
#pragma unroll
      for (int v = 0; v < 4; ++v) s[ct][v] = acc[v];
    }
    if (t == qt) {
      const int rbase = w * 16 + kg * 4;
#pragma unroll
      for (int ct = 0; ct < 4; ++ct) {
        const int key = ct * 16 + cl;
#pragma unroll
        for (int v = 0; v < 4; ++v)
          if (key > rbase + v) s[ct][v] = -1e30f;
      }
    }
    float corr[4];
#pragma unroll
    for (int v = 0; v < 4; ++v) {
      float x = fmaxf(fmaxf(s[0][v], s[1][v]), fmaxf(s[2][v], s[3][v]));
#pragma unroll
      for (int off = 1; off < 16; off <<= 1) x = fmaxf(x, __shfl_xor(x, off));
      const float mn = fmaxf(mrow[v], x);
      corr[v] = __expf(mrow[v] - mn);
      mrow[v] = mn;
    }
    float rs[4] = {0.f, 0.f, 0.f, 0.f};
    u16 pb[4][4];
#pragma unroll
    for (int ct = 0; ct < 4; ++ct)
#pragma unroll
      for (int v = 0; v < 4; ++v) {
        const float p = __expf(s[ct][v] - mrow[v]);
        rs[v] += p;
        pb[ct][v] = f2bf(p);
      }
#pragma unroll
    for (int v = 0; v < 4; ++v) {
      float x = rs[v];
#pragma unroll
      for (int off = 1; off < 16; off <<= 1) x += __shfl_xor(x, off);
      lrow[v] = lrow[v] * corr[v] + x;
    }
#pragma unroll
    for (int dt = 0; dt < 8; ++dt)
#pragma unroll
      for (int v = 0; v < 4; ++v) o[dt][v] *= corr[v];

    u16* pw = &lp[w][0];
#pragma unroll
    for (int ct = 0; ct < 4; ++ct)
#pragma unroll
      for (int v = 0; v < 4; ++v) {
        const int r = kg * 4 + v;
        const int cc = ct * 16 + cl;
        pw[r * KVBLK + (cc ^ ((r & 7) * 8))] = pb[ct][v];
      }
    bf16x8 pa[2];
#pragma unroll
    for (int kc2 = 0; kc2 < 2; ++kc2) {
      const int c0 = (kc2 * 32 + kg * 8) ^ ((cl & 7) * 8);
      pa[kc2] = *(const bf16x8*)&pw[cl * KVBLK + c0];
    }
#pragma unroll
    for (int dt = 0; dt < 8; ++dt) {
      const int d = dt * 16 + cl;
#pragma unroll
      for (int kc2 = 0; kc2 < 2; ++kc2) {
        const int c0 = (kc2 * 32 + kg * 8) ^ ((d & 7) * 8);
        bf16x8 vf = *(const bf16x8*)&lv[d * KVBLK + c0];
        o[dt] = __builtin_amdgcn_mfma_f32_16x16x32_bf16(pa[kc2], vf, o[dt], 0, 0, 0);
      }
    }
  }

#pragma unroll
  for (int v = 0; v < 4; ++v) {
    const float inv = 1.0f / lrow[v];
    const int tq = qbase + w * 16 + kg * 4 + v;
    float* op = outg + ((size_t)(b * SEQ + tq) * NHQ + hq) * DH;
#pragma unroll
    for (int dt = 0; dt < 8; ++dt) op[dt * 16 + cl] = o[dt][v] * inv;
  }
}

extern "C" void kernel_launch(void* const* d_in, const int* in_sizes, int n_in,
                              void* d_out, int out_size, void* d_ws, size_t ws_size,
                              hipStream_t stream) {
  const float* q  = (const float*)d_in[0];
  const float* kc = (const float*)d_in[1];
  const float* vc = (const float*)d_in[2];
  const int*   bt = (const int*)d_in[3];
  float* out = (float*)d_out;
  const size_t kv_elems = (size_t)NBLK * NHK * BSZ * DH;
  const size_t need = 2 * kv_elems * sizeof(u16);   // 16.8 MB
  if (ws_size >= need) {
    u16* kb  = (u16*)d_ws;
    u16* vbT = kb + kv_elems;
    const int total_quads = NBLK * BSZ * NHK * (DH / 4);
    prep_kv<<<total_quads / 256, 256, 0, stream>>>(kc, vc, kb, vbT);
    attn_fwd_pre<<<dim3(512), 256, 0, stream>>>(q, kb, vbT, bt, out);
  } else {
    dim3 grid_fb(SEQ / 64, NHQ, 4 /*B*/);
    attn_fwd_fb<<<grid_fb, 256, 0, stream>>>(q, kc, vc, bt, out);
  }
}

// Round 9
// 98.402 us; speedup vs baseline: 2.6719x; 1.8500x over previous
//
#include <hip/hip_runtime.h>

// Flash-attention fwd, causal GQA, paged KV. fp32 in/out, bf16 MFMA compute.
// Round 9: round-8's 48KB LDS (K dbuf 2x16KB + V single 16KB) + round-5's
// register config __launch_bounds__(256,2) (proven 128 VGPR, no spill).
// 48KB -> 3 blocks/CU; 128 regs -> 4 waves/SIMD capacity -> 12 waves/CU.
// Grid 1024 (1 item/block), qc-descending dispatch = LPT dynamic balance.
// Core: 32x32 swapped MFMA, in-reg softmax (permlane32_swap), T12 cvt_pk,
// T13 defer-max, K swizzle &15 / V swizzle &7, bf16 KV preprocessed in d_ws.

#define SEQ   1024
#define NHQ   32
#define NHK   8
#define DH    128
#define BSZ   256
#define NBLK  16
#define QBLK  128
#define KVBLK 64
#define SCALE  0.0883883476483184f           // 1/sqrt(128)
#define SCLOG2 0.12752551286084812f          // SCALE * log2(e)

typedef __attribute__((ext_vector_type(8)))  short bf16x8;
typedef __attribute__((ext_vector_type(4)))  float f32x4;
typedef __attribute__((ext_vector_type(16))) float f32x16;
typedef __attribute__((ext_vector_type(2)))  unsigned int u32x2;
typedef unsigned short u16;
typedef unsigned int u32;
typedef unsigned long long u64;

static __device__ __forceinline__ u16 f2bf(float f) {
  union { float f; u32 u; } x; x.f = f;
  return (u16)((x.u + 0x7fffu + ((x.u >> 16) & 1u)) >> 16);  // RNE
}

static __device__ __forceinline__ u32 cvtpk(float a, float b) {
  u32 r;
  asm("v_cvt_pk_bf16_f32 %0, %1, %2" : "=v"(r) : "v"(a), "v"(b));
  return r;
}

static __device__ __forceinline__ void gload16(const u16* src, u16* dst_lds) {
  __builtin_amdgcn_global_load_lds(
      (const __attribute__((address_space(1))) u32*)src,
      (__attribute__((address_space(3))) u32*)dst_lds, 16, 0, 0);
}

// ---------------- preprocess: fp32 KV -> bf16 K[nb][hk][key][d], V^T[nb][hk][d][key] ----------------
__global__ void prep_kv(const float* __restrict__ kc, const float* __restrict__ vc,
                        u16* __restrict__ kb, u16* __restrict__ vbT) {
  const int idx = blockIdx.x * 256 + threadIdx.x;   // (nb, key, hk, d4), d4 fastest
  const int d4  = idx & 31;
  const int hk  = (idx >> 5) & 7;
  const int key = (idx >> 8) & 255;
  const int nb  = idx >> 16;
  f32x4 kx = *(const f32x4*)(kc + (size_t)idx * 4);
  f32x4 vx = *(const f32x4*)(vc + (size_t)idx * 4);
  u64 pk = (u64)f2bf(kx[0]) | ((u64)f2bf(kx[1]) << 16) |
           ((u64)f2bf(kx[2]) << 32) | ((u64)f2bf(kx[3]) << 48);
  *(u64*)(kb + (((size_t)(nb * NHK + hk) * BSZ + key) * DH + 4 * d4)) = pk;
#pragma unroll
  for (int j = 0; j < 4; ++j)
    vbT[((size_t)(nb * NHK + hk) * DH + 4 * d4 + j) * BSZ + key] = f2bf(vx[j]);
}

// ---------------- main attention: 4 warps x 32 q-rows, 1 item/block ----------------
__global__ __launch_bounds__(256, 2)
void attn_fwd_pre(const float* __restrict__ qg,
                  const u16* __restrict__ kbg,
                  const u16* __restrict__ vbT,
                  const int* __restrict__ btab,
                  float* __restrict__ outg)
{
  __shared__ u16 lk[2][KVBLK * DH];   // 2 x 16 KB, K [key][d], slot-swizzled (&15)
  __shared__ u16 lv[DH * KVBLK];      // 16 KB, V^T [d][key], slot-swizzled (&7)

  const int tid  = threadIdx.x;
  const int lane = tid & 63;
  const int w    = tid >> 6;     // 0..3
  const int ln   = lane & 31;
  const int hi   = lane >> 5;
  const int bid  = blockIdx.x;   // 0..1023, qc-descending

  const int qc = 7 - (bid >> 7);
  const int rr = bid & 127;
  const int hq = rr >> 2;
  const int b  = rr & 3;
  const int hk = hq >> 2;

  const int rg = qc * QBLK + w * 32 + ln;      // this lane's q-row (absolute)

  // ---- Q fragments (B-operand): qf[dc][j] = Q[rg][dc*16 + hi*8 + j] * SCLOG2 ----
  bf16x8 qf[8];
  {
    const float* qp = qg + ((size_t)(b * SEQ + rg) * NHQ + hq) * DH;
#pragma unroll
    for (int dc = 0; dc < 8; ++dc) {
      const int d0 = dc * 16 + hi * 8;
      f32x4 x0 = *(const f32x4*)(qp + d0);
      f32x4 x1 = *(const f32x4*)(qp + d0 + 4);
      bf16x8 f;
#pragma unroll
      for (int j = 0; j < 4; ++j) {
        f[j]     = (short)f2bf(x0[j] * SCLOG2);
        f[j + 4] = (short)f2bf(x1[j] * SCLOG2);
      }
      qf[dc] = f;
    }
  }

  f32x16 o[4];
#pragma unroll
  for (int db = 0; db < 4; ++db)
#pragma unroll
    for (int i = 0; i < 16; ++i) o[db][i] = 0.f;
  float m = -1e30f, l = 0.f;

  const u16* kbh = kbg + (size_t)hk * BSZ * DH;
  const u16* vbh = vbT + (size_t)hk * DH * BSZ;

  // K stage (tile t -> buffer c): 4 gload_lds per warp, pre-swizzled source.
  auto stage_k = [&](int t, int c) {
    const int nb   = btab[b * (SEQ / BSZ) + (t >> 2)];
    const int off0 = (t & 3) * KVBLK;
    const u16* ksrc = kbh + (size_t)nb * (NHK * BSZ * DH) + (size_t)off0 * DH;
#pragma unroll
    for (int i = 0; i < 4; ++i) {
      const int kbs = w * 16 + i * 4;
      const int key = kbs + (lane >> 4);
      const u16* src = ksrc + key * DH + 8 * ((lane & 15) ^ (key & 15));
      gload16(src, &lk[c][kbs * DH]);
    }
  };
  // V stage (tile t, single buffer): 4 gload_lds per warp.
  auto stage_v = [&](int t) {
    const int nb   = btab[b * (SEQ / BSZ) + (t >> 2)];
    const int off0 = (t & 3) * KVBLK;
    const u16* vsrc = vbh + (size_t)nb * (NHK * DH * BSZ) + off0;
#pragma unroll
    for (int i = 0; i < 4; ++i) {
      const int dbs = w * 32 + i * 8;
      const int d   = dbs + (lane >> 3);
      const u16* src = vsrc + d * BSZ + 8 * ((lane & 7) ^ (d & 7));
      gload16(src, &lv[dbs * KVBLK]);
    }
  };

  const int ntile = 2 * qc + 2;
  const int tmaxw = 2 * qc + (w >> 1);   // last tile this warp computes

  stage_k(0, 0);
  __syncthreads();                       // K(0) resident

  for (int t = 0; t < ntile; ++t) {
    const int c = t & 1;
    const bool live = (t <= tmaxw);

    stage_v(t);                          // V(t) -> lv (latency hides under QKT)
    if (t + 1 < ntile) stage_k(t + 1, c ^ 1);

    f32x16 sa[2];
    if (live) {
      // ---- S^T = K·Q (swapped): lane holds S[rg][key] for 32 keys per kb ----
      __builtin_amdgcn_s_setprio(1);
#pragma unroll
      for (int kb = 0; kb < 2; ++kb) {
        f32x16 acc;
#pragma unroll
        for (int i = 0; i < 16; ++i) acc[i] = 0.f;
        const int key  = kb * 32 + ln;
        const int srow = key * DH;
        const int sw   = (key & 15) * 8;
#pragma unroll
        for (int dc = 0; dc < 8; ++dc) {
          const int d0 = dc * 16 + hi * 8;
          bf16x8 kf = *(const bf16x8*)&lk[c][srow + (d0 ^ sw)];
          acc = __builtin_amdgcn_mfma_f32_32x32x16_bf16(kf, qf[dc], acc, 0, 0, 0);
        }
        sa[kb] = acc;
      }
      __builtin_amdgcn_s_setprio(0);

      // ---- causal mask (diagonal tile only) ----
      if (t == tmaxw) {
        const int kt = t * KVBLK;
#pragma unroll
        for (int kb = 0; kb < 2; ++kb)
#pragma unroll
          for (int r = 0; r < 16; ++r) {
            const int kglob = kt + kb * 32 + (r & 3) + 8 * (r >> 2) + 4 * hi;
            if (kglob > rg) sa[kb][r] = -1e30f;
          }
      }

      // ---- row max: max3-friendly tree + one partner swap ----
      float mx[8];
#pragma unroll
      for (int i = 0; i < 8; ++i)
        mx[i] = fmaxf(fmaxf(sa[0][i], sa[0][i + 8]), fmaxf(sa[1][i], sa[1][i + 8]));
      float m0 = fmaxf(fmaxf(mx[0], mx[1]), fmaxf(mx[2], mx[3]));
      float m1 = fmaxf(fmaxf(mx[4], mx[5]), fmaxf(mx[6], mx[7]));
      m0 = fmaxf(m0, m1);
      u32x2 xr = __builtin_amdgcn_permlane32_swap(
          __float_as_uint(m0), __float_as_uint(m0), false, false);
      const float tmax = fmaxf(__uint_as_float(xr[0]), __uint_as_float(xr[1]));

      // ---- deferred rescale (T13; log2 domain, THR=11 bits ~ e^7.6) ----
      if (tmax > m + 11.0f) {
        const float corr = exp2f(m - tmax);
        m = tmax;
        l *= corr;
#pragma unroll
        for (int db = 0; db < 4; ++db)
#pragma unroll
          for (int i = 0; i < 16; ++i) o[db][i] *= corr;
      }

      // ---- P = 2^(s - m); row sum (in-lane tree + partner swap) ----
      float sm[16];
#pragma unroll
      for (int i = 0; i < 16; ++i) {
        sa[0][i] = exp2f(sa[0][i] - m);
        sa[1][i] = exp2f(sa[1][i] - m);
        sm[i] = sa[0][i] + sa[1][i];
      }
#pragma unroll
      for (int st = 8; st >= 1; st >>= 1)
#pragma unroll
        for (int i = 0; i < st; ++i) sm[i] += sm[i + st];
      u32x2 sr = __builtin_amdgcn_permlane32_swap(
          __float_as_uint(sm[0]), __float_as_uint(sm[0]), false, false);
      l += __uint_as_float(sr[0]) + __uint_as_float(sr[1]);
    }

    __syncthreads();   // barrier A: V(t) (and K(t+1)) drained; lv readable

    if (live) {
      // ---- PV: O^T += V^T · P^T ; P->B-frag via cvt_pk + permlane32_swap (T12) ----
#pragma unroll
      for (int kc = 0; kc < 4; ++kc) {
        const int kb = kc >> 1, cc = kc & 1;
        const u32 x0 = cvtpk(sa[kb][8 * cc + 0], sa[kb][8 * cc + 1]);
        const u32 y0 = cvtpk(sa[kb][8 * cc + 4], sa[kb][8 * cc + 5]);
        const u32 x1 = cvtpk(sa[kb][8 * cc + 2], sa[kb][8 * cc + 3]);
        const u32 y1 = cvtpk(sa[kb][8 * cc + 6], sa[kb][8 * cc + 7]);
        u32x2 r0 = __builtin_amdgcn_permlane32_swap(x0, y0, false, false);
        u32x2 r1 = __builtin_amdgcn_permlane32_swap(x1, y1, false, false);
        union { bf16x8 v; u32 u[4]; } pb;
        pb.u[0] = r0[0]; pb.u[1] = r1[0]; pb.u[2] = r0[1]; pb.u[3] = r1[1];
        const int k0 = kc * 16 + hi * 8;
        __builtin_amdgcn_s_setprio(1);
#pragma unroll
        for (int db = 0; db < 4; ++db) {
          const int d = db * 32 + ln;
          bf16x8 vf = *(const bf16x8*)&lv[d * KVBLK + (k0 ^ ((d & 7) * 8))];
          o[db] = __builtin_amdgcn_mfma_f32_32x32x16_bf16(vf, pb.v, o[db], 0, 0, 0);
        }
        __builtin_amdgcn_s_setprio(0);
      }
    }

    __syncthreads();   // barrier B: lv reads done before next stage_v overwrite
  }

  // ---- epilogue: O[rg][d] / l ; d = db*32 + (reg&3) + 8*(reg>>2) + 4*hi ----
  const float inv = 1.0f / l;
  float* op = outg + ((size_t)(b * SEQ + rg) * NHQ + hq) * DH;
#pragma unroll
  for (int db = 0; db < 4; ++db)
#pragma unroll
    for (int q4 = 0; q4 < 4; ++q4) {
      f32x4 val;
#pragma unroll
      for (int r2 = 0; r2 < 4; ++r2) val[r2] = o[db][q4 * 4 + r2] * inv;
      *(f32x4*)(op + db * 32 + q4 * 8 + hi * 4) = val;
    }
}

// ---------------- fallback (fp32 caches, no ws), round-1 structure ----------------
__global__ __launch_bounds__(256, 2)
void attn_fwd_fb(const float* __restrict__ qg,
                 const float* __restrict__ kcache,
                 const float* __restrict__ vcache,
                 const int*   __restrict__ btab,
                 float* __restrict__ outg)
{
  __shared__ u16 lk[KVBLK * DH];
  __shared__ u16 lv[DH * KVBLK];
  __shared__ u16 lp[4][16 * KVBLK];

  const int tid  = threadIdx.x;
  const int lane = tid & 63;
  const int w    = tid >> 6;
  const int qt   = blockIdx.x;
  const int hq   = blockIdx.y;
  const int b    = blockIdx.z;
  const int hk   = hq >> 2;
  const int qbase = qt * 64;
  const int cl = lane & 15;
  const int kg = lane >> 4;

  bf16x8 qf[4];
  {
    const int tq = qbase + w * 16 + cl;
    const float* qp = qg + ((size_t)(b * SEQ + tq) * NHQ + hq) * DH;
#pragma unroll
    for (int dc = 0; dc < 4; ++dc) {
      const int d0 = dc * 32 + kg * 8;
      f32x4 x0 = *(const f32x4*)(qp + d0);
      f32x4 x1 = *(const f32x4*)(qp + d0 + 4);
      bf16x8 f;
#pragma unroll
      for (int j = 0; j < 4; ++j) { f[j] = (short)f2bf(x0[j] * SCALE); f[j + 4] = (short)f2bf(x1[j] * SCALE); }
      qf[dc] = f;
    }
  }

  f32x4 o[8];
#pragma unroll
  for (int i = 0; i < 8; ++i) o[i] = (f32x4){0.f, 0.f, 0.f, 0.f};
  float mrow[4] = {-1e30f, -1e30f, -1e30f, -1e30f};
  float lrow[4] = {0.f, 0.f, 0.f, 0.f};

  const int ntile = qt + 1;
  for (int t = 0; t < ntile; ++t) {
    __syncthreads();
    {
      const int nb   = btab[b * (SEQ / BSZ) + ((t * KVBLK) / BSZ)];
      const int off0 = (t * KVBLK) % BSZ;
      const int d4 = tid & 31;
      const int kl = tid >> 5;
      const float* kbp = kcache + (((size_t)nb * BSZ + off0) * NHK + hk) * DH + d4 * 4;
      const float* vbp = vcache + (((size_t)nb * BSZ + off0) * NHK + hk) * DH + d4 * 4;
#pragma unroll
      for (int p = 0; p < 8; ++p) {
        const int key = p * 8 + kl;
        const size_t go = (size_t)key * (NHK * DH);
        f32x4 kx = *(const f32x4*)(kbp + go);
        f32x4 vx = *(const f32x4*)(vbp + go);
        u32 w0 = (u32)f2bf(kx[0]) | ((u32)f2bf(kx[1]) << 16);
        u32 w1 = (u32)f2bf(kx[2]) | ((u32)f2bf(kx[3]) << 16);
        const int doff = (4 * d4) ^ ((key & 7) * 8);
        u64 pk = (u64)w0 | ((u64)w1 << 32);
        *(u64*)&lk[key * DH + doff] = pk;
#pragma unroll
        for (int j = 0; j < 4; ++j) {
          const int d = 4 * d4 + j;
          lv[d * KVBLK + (key ^ ((d & 7) * 8))] = f2bf(vx[j]);
        }
      }
    }
    __syncthreads();

    float s[4][4];
#pragma unroll
    for (int ct = 0; ct < 4; ++ct) {
      f32x4 acc = (f32x4){0.f, 0.f, 0.f, 0.f};
      const int key = ct * 16 + cl;
#pragma unroll
      for (int dc = 0; dc < 4; ++dc) {
        const int d0 = (dc * 32 + kg * 8) ^ ((key & 7) * 8);
        bf16x8 kf = *(const bf16x8*)&lk[key * DH + d0];
        acc = __builtin_amdgcn_mfma_f32_16x16x32_bf16(qf[dc], kf, acc, 0, 0, 0);
      }
#pragma unroll
      for (int v = 0; v < 4; ++v) s[ct][v] = acc[v];
    }
    if (t == qt) {
      const int rbase = w * 16 + kg * 4;
#pragma unroll
      for (int ct = 0; ct < 4; ++ct) {
        const int key = ct * 16 + cl;
#pragma unroll
        for (int v = 0; v < 4; ++v)
          if (key > rbase + v) s[ct][v] = -1e30f;
      }
    }
    float corr[4];
#pragma unroll
    for (int v = 0; v < 4; ++v) {
      float x = fmaxf(fmaxf(s[0][v], s[1][v]), fmaxf(s[2][v], s[3][v]));
#pragma unroll
      for (int off = 1; off < 16; off <<= 1) x = fmaxf(x, __shfl_xor(x, off));
      const float mn = fmaxf(mrow[v], x);
      corr[v] = __expf(mrow[v] - mn);
      mrow[v] = mn;
    }
    float rs[4] = {0.f, 0.f, 0.f, 0.f};
    u16 pb[4][4];
#pragma unroll
    for (int ct = 0; ct < 4; ++ct)
#pragma unroll
      for (int v = 0; v < 4; ++v) {
        const float p = __expf(s[ct][v] - mrow[v]);
        rs[v] += p;
        pb[ct][v] = f2bf(p);
      }
#pragma unroll
    for (int v = 0; v < 4; ++v) {
      float x = rs[v];
#pragma unroll
      for (int off = 1; off < 16; off <<= 1) x += __shfl_xor(x, off);
      lrow[v] = lrow[v] * corr[v] + x;
    }
#pragma unroll
    for (int dt = 0; dt < 8; ++dt)
#pragma unroll
      for (int v = 0; v < 4; ++v) o[dt][v] *= corr[v];

    u16* pw = &lp[w][0];
#pragma unroll
    for (int ct = 0; ct < 4; ++ct)
#pragma unroll
      for (int v = 0; v < 4; ++v) {
        const int r = kg * 4 + v;
        const int cc = ct * 16 + cl;
        pw[r * KVBLK + (cc ^ ((r & 7) * 8))] = pb[ct][v];
      }
    bf16x8 pa[2];
#pragma unroll
    for (int kc2 = 0; kc2 < 2; ++kc2) {
      const int c0 = (kc2 * 32 + kg * 8) ^ ((cl & 7) * 8);
      pa[kc2] = *(const bf16x8*)&pw[cl * KVBLK + c0];
    }
#pragma unroll
    for (int dt = 0; dt < 8; ++dt) {
      const int d = dt * 16 + cl;
#pragma unroll
      for (int kc2 = 0; kc2 < 2; ++kc2) {
        const int c0 = (kc2 * 32 + kg * 8) ^ ((d & 7) * 8);
        bf16x8 vf = *(const bf16x8*)&lv[d * KVBLK + c0];
        o[dt] = __builtin_amdgcn_mfma_f32_16x16x32_bf16(pa[kc2], vf, o[dt], 0, 0, 0);
      }
    }
  }

#pragma unroll
  for (int v = 0; v < 4; ++v) {
    const float inv = 1.0f / lrow[v];
    const int tq = qbase + w * 16 + kg * 4 + v;
    float* op = outg + ((size_t)(b * SEQ + tq) * NHQ + hq) * DH;
#pragma unroll
    for (int dt = 0; dt < 8; ++dt) op[dt * 16 + cl] = o[dt][v] * inv;
  }
}

extern "C" void kernel_launch(void* const* d_in, const int* in_sizes, int n_in,
                              void* d_out, int out_size, void* d_ws, size_t ws_size,
                              hipStream_t stream) {
  const float* q  = (const float*)d_in[0];
  const float* kc = (const float*)d_in[1];
  const float* vc = (const float*)d_in[2];
  const int*   bt = (const int*)d_in[3];
  float* out = (float*)d_out;
  const size_t kv_elems = (size_t)NBLK * NHK * BSZ * DH;
  const size_t need = 2 * kv_elems * sizeof(u16);   // 16.8 MB
  if (ws_size >= need) {
    u16* kb  = (u16*)d_ws;
    u16* vbT = kb + kv_elems;
    const int total_quads = NBLK * BSZ * NHK * (DH / 4);
    prep_kv<<<total_quads / 256, 256, 0, stream>>>(kc, vc, kb, vbT);
    attn_fwd_pre<<<dim3(1024), 256, 0, stream>>>(q, kb, vbT, bt, out);
  } else {
    dim3 grid_fb(SEQ / 64, NHQ, 4 /*B*/);
    attn_fwd_fb<<<grid_fb, 256, 0, stream>>>(q, kc, vc, bt, out);
  }
}